// Round 1
// baseline (76.205 us; speedup 1.0000x reference)
//
#include <hip/hip_runtime.h>
#include <math.h>

// MultiObjectPointMatchingLoss: loss = mean_{b,n} || (R_pred[b]-R_gt[b]) @ p[c_b,n] ||
// B=1024, C=21, N=4096. bank = 1MB (L2-resident). Launch-latency regime.
// R7: fuse finalize into the main kernel via last-block-done pattern.
//  - per-wave partials stored with agent-scope (sc1) stores, acked via vmcnt(0)
//    BEFORE the per-block counter increment (so count==grid-1 implies all
//    partials are at the coherence point).
//  - ONE relaxed int atomic per block (1024 total, staggered) — not the 4096
//    same-address float RMWs that made R4/R5's atomic tail costly.
//  - last block: __threadfence() acquire (L1/L2 inv), then the EXACT old
//    finalize body (same summation order -> deterministic, absmax 0 preserved).
//  - 4-byte counter re-zeroed by a hipMemsetAsync node (replaces the finalize
//    dispatch; graph-capture safe).

__device__ __forceinline__ void quat_to_R(float x, float y, float z, float w, float R[9]) {
    R[0] = 1.0f - 2.0f * (y * y + z * z);
    R[1] = 2.0f * (x * y - w * z);
    R[2] = 2.0f * (x * z + w * y);
    R[3] = 2.0f * (x * y + w * z);
    R[4] = 1.0f - 2.0f * (x * x + z * z);
    R[5] = 2.0f * (y * z - w * x);
    R[6] = 2.0f * (x * z - w * y);
    R[7] = 2.0f * (y * z + w * x);
    R[8] = 1.0f - 2.0f * (x * x + y * y);
}

__device__ __forceinline__ float norm3(const float D[9], float p0, float p1, float p2) {
    const float d0 = D[0] * p0 + D[1] * p1 + D[2] * p2;
    const float d1 = D[3] * p0 + D[4] * p1 + D[5] * p2;
    const float d2 = D[6] * p0 + D[7] * p1 + D[8] * p2;
    return __builtin_amdgcn_sqrtf(d0 * d0 + d1 * d1 + d2 * d2);
}

__global__ __launch_bounds__(256) void pm_loss_fused(
    const float* __restrict__ pred_q,
    const float* __restrict__ gt_q,
    const int*   __restrict__ cls,
    const float* __restrict__ bank,
    float*       __restrict__ partials,   // 4 per block (one per wave), pre-scaled
    unsigned int* __restrict__ counter,   // zeroed by memset node each call
    float*       __restrict__ out,
    int N, float scale)
{
    const int b = blockIdx.x;

    const float px = pred_q[b * 4 + 0], py = pred_q[b * 4 + 1];
    const float pz = pred_q[b * 4 + 2], pw = pred_q[b * 4 + 3];
    const float gx = gt_q[b * 4 + 0],  gy = gt_q[b * 4 + 1];
    const float gz = gt_q[b * 4 + 2],  gw = gt_q[b * 4 + 3];

    float Rp[9], Rg[9], D[9];
    quat_to_R(px, py, pz, pw, Rp);
    quat_to_R(gx, gy, gz, gw, Rg);
    #pragma unroll
    for (int i = 0; i < 9; ++i) D[i] = Rp[i] - Rg[i];

    const float* __restrict__ pts = bank + (size_t)cls[b] * (size_t)N * 3;

    const int t = threadIdx.x;
    float acc = 0.0f;

    // 4 points per thread per iteration: 3x float4 = 48B contiguous per lane.
    const int ptsPerIter = 256 * 4;                  // 1024
    const int nAligned   = (N / ptsPerIter) * ptsPerIter;
    for (int i = 0; i < nAligned; i += ptsPerIter) {
        const int n0 = i + t * 4;
        const float4* __restrict__ p4 = (const float4*)(pts + (size_t)n0 * 3);
        const float4 a  = p4[0];
        const float4 v  = p4[1];
        const float4 c4 = p4[2];
        acc += norm3(D, a.x, a.y, a.z);
        acc += norm3(D, a.w, v.x, v.y);
        acc += norm3(D, v.z, v.w, c4.x);
        acc += norm3(D, c4.y, c4.z, c4.w);
    }
    // tail (not taken for N=4096)
    for (int n = nAligned + t; n < N; n += 256) {
        acc += norm3(D, pts[n * 3 + 0], pts[n * 3 + 1], pts[n * 3 + 2]);
    }

    // wave-level shuffle reduce; no LDS for the partial itself
    #pragma unroll
    for (int off = 32; off > 0; off >>= 1)
        acc += __shfl_down(acc, off, 64);

    if ((t & 63) == 0) {
        // agent-scope (sc1) store: lands at the coherence point, not dirty in
        // this XCD's L2, so the last block's acquire-invalidate will see it.
        __hip_atomic_store(&partials[blockIdx.x * 4 + (t >> 6)], acc * scale,
                           __ATOMIC_RELAXED, __HIP_MEMORY_SCOPE_AGENT);
    }
    // Ack all of this wave's outstanding vmem (incl. the sc1 partial store)
    // before the block signals completion.
    asm volatile("s_waitcnt vmcnt(0)" ::: "memory");
    __syncthreads();

    __shared__ unsigned int s_old;
    if (t == 0) {
        s_old = __hip_atomic_fetch_add(counter, 1u,
                                       __ATOMIC_RELAXED, __HIP_MEMORY_SCOPE_AGENT);
    }
    __syncthreads();

    if (s_old != (unsigned int)(gridDim.x - 1)) return;   // not the last block
    if (t >= 64) return;                                  // finalize on wave 0 only

    // Acquire: invalidate stale L1/L2 so plain vector loads below observe the
    // sc1-acked partials from all XCDs.
    __threadfence();

    // EXACT old finalize body (same order -> bitwise-identical result).
    const float4* __restrict__ p4 = (const float4*)partials;  // 1024 float4s
    float facc = 0.0f;
    #pragma unroll
    for (int i = 0; i < 16; ++i) {        // 16 independent coalesced loads
        const float4 v = p4[i * 64 + t];
        facc += (v.x + v.y) + (v.z + v.w);
    }
    #pragma unroll
    for (int off = 32; off > 0; off >>= 1)
        facc += __shfl_down(facc, off, 64);
    if (t == 0) out[0] = facc;
}

extern "C" void kernel_launch(void* const* d_in, const int* in_sizes, int n_in,
                              void* d_out, int out_size, void* d_ws, size_t ws_size,
                              hipStream_t stream) {
    const float* pred_q = (const float*)d_in[0];
    const float* gt_q   = (const float*)d_in[1];
    const int*   cls    = (const int*)d_in[2];
    const float* bank   = (const float*)d_in[3];

    const int B = in_sizes[0] / 4;           // 1024
    const int N = in_sizes[3] / (21 * 3);    // 4096 (C=21 fixed by reference)

    float*        partials = (float*)d_ws;                       // 4*B floats
    unsigned int* counter  = (unsigned int*)((char*)d_ws + 16384); // separate line

    hipMemsetAsync(counter, 0, sizeof(unsigned int), stream);

    const float scale = 1.0f / ((float)B * (float)N);
    pm_loss_fused<<<B, 256, 0, stream>>>(pred_q, gt_q, cls, bank,
                                         partials, counter, (float*)d_out, N, scale);
}